// Round 2
// baseline (852.941 us; speedup 1.0000x reference)
//
#include <hip/hip_runtime.h>

// GCMCGraphConv: out[d] = ci[d] * sum_{e: dst[e]==d} weight[node_ids[src[e]]] * cj[src[e]]
// N_SRC = N_DST = 100000, N_EDGES = 3.2M, OUT_DIM = 64.
//
// Strategy: build CSR-by-dst in workspace each launch (hist -> scan -> scatter),
// then pull-mode gather: one wave per dst, register accumulation, zero atomics
// on the 64-wide feature data. Atomics only on scalar int counters (L2-resident).

#define OUT_DIM 64

// ---- 1) histogram of dst ----
__global__ void __launch_bounds__(256) gcmc_hist(
    const int* __restrict__ dst_idx, int* __restrict__ cnt, int n_edges) {
  int i = blockIdx.x * blockDim.x + threadIdx.x;
  const int stride = gridDim.x * blockDim.x;
  for (; i < n_edges; i += stride) {
    atomicAdd(&cnt[dst_idx[i]], 1);
  }
}

// ---- 2) single-block exclusive scan: cnt[n] -> off[n+1], pos[n]=off[n] ----
__global__ void __launch_bounds__(1024) gcmc_scan(
    const int* __restrict__ cnt, int* __restrict__ off, int* __restrict__ pos,
    int n) {
  __shared__ int lds[1024];
  const int tid = threadIdx.x;
  int carry = 0;
  for (int base = 0; base < n; base += 1024) {
    const int i = base + tid;
    const int v = (i < n) ? cnt[i] : 0;
    lds[tid] = v;
    __syncthreads();
#pragma unroll
    for (int d = 1; d < 1024; d <<= 1) {
      const int t = (tid >= d) ? lds[tid - d] : 0;
      __syncthreads();
      lds[tid] += t;
      __syncthreads();
    }
    const int excl = lds[tid] - v + carry;
    if (i < n) {
      off[i] = excl;
      pos[i] = excl;
    }
    carry += lds[1023];  // block-uniform
    __syncthreads();     // protect lds before next tile overwrites
  }
  if (tid == 0) off[n] = carry;
}

// ---- 3) scatter src indices into dst-sorted order ----
__global__ void __launch_bounds__(256) gcmc_scatter(
    const int* __restrict__ dst_idx, const int* __restrict__ src_idx,
    int* __restrict__ pos, int* __restrict__ src_sorted, int n_edges) {
  int i = blockIdx.x * blockDim.x + threadIdx.x;
  const int stride = gridDim.x * blockDim.x;
  for (; i < n_edges; i += stride) {
    const int p = atomicAdd(&pos[dst_idx[i]], 1);
    src_sorted[p] = src_idx[i];
  }
}

// ---- 4) pull-mode gather: one wave per dst, fused ci scale ----
__global__ void __launch_bounds__(256) gcmc_gather(
    const int* __restrict__ off, const int* __restrict__ src_sorted,
    const int* __restrict__ node_ids, const float* __restrict__ cj,
    const float* __restrict__ weight, const float* __restrict__ ci,
    float* __restrict__ out, int n_dst) {
  const int lane = threadIdx.x & 63;
  const int wpb = blockDim.x >> 6;
  const int wave = blockIdx.x * wpb + (threadIdx.x >> 6);
  const int nwaves = gridDim.x * wpb;

  for (int d = wave; d < n_dst; d += nwaves) {
    const int b = off[d];
    const int e = off[d + 1];
    float acc0 = 0.f, acc1 = 0.f;
    int k = b;
    // 2-way unroll: two independent dependent-load chains for ILP
    for (; k + 1 < e; k += 2) {
      const int s0 = src_sorted[k];
      const int s1 = src_sorted[k + 1];
      const int r0 = node_ids[s0];
      const int r1 = node_ids[s1];
      const float c0 = cj[s0];
      const float c1 = cj[s1];
      acc0 += weight[r0 * OUT_DIM + lane] * c0;
      acc1 += weight[r1 * OUT_DIM + lane] * c1;
    }
    if (k < e) {
      const int s = src_sorted[k];
      acc0 += weight[node_ids[s] * OUT_DIM + lane] * cj[s];
    }
    out[d * OUT_DIM + lane] = (acc0 + acc1) * ci[d];
  }
}

extern "C" void kernel_launch(void* const* d_in, const int* in_sizes, int n_in,
                              void* d_out, int out_size, void* d_ws, size_t ws_size,
                              hipStream_t stream) {
  const int* node_ids = (const int*)d_in[0];
  const int* src_idx  = (const int*)d_in[1];
  const int* dst_idx  = (const int*)d_in[2];
  const float* cj     = (const float*)d_in[3];
  const float* ci     = (const float*)d_in[4];
  const float* weight = (const float*)d_in[5];
  float* out = (float*)d_out;

  const int n_edges = in_sizes[1];
  const int n_dst = out_size / OUT_DIM;

  // workspace layout (ints): cnt[n_dst] | off[n_dst+1] | pos[n_dst] | src_sorted[n_edges]
  int* cnt = (int*)d_ws;
  int* off = cnt + n_dst;
  int* pos = off + (n_dst + 1);
  int* src_sorted = pos + n_dst;
  // total = (3*n_dst + 1 + n_edges) * 4 B ~= 14 MB

  // zero the histogram (ws is poisoned 0xAA each call)
  hipMemsetAsync(cnt, 0, (size_t)n_dst * sizeof(int), stream);

  {
    const int block = 256;
    const int grid = 2048;
    gcmc_hist<<<grid, block, 0, stream>>>(dst_idx, cnt, n_edges);
  }

  gcmc_scan<<<1, 1024, 0, stream>>>(cnt, off, pos, n_dst);

  {
    const int block = 256;
    const int grid = 2048;
    gcmc_scatter<<<grid, block, 0, stream>>>(dst_idx, src_idx, pos, src_sorted,
                                             n_edges);
  }

  {
    const int block = 256;  // 4 waves/block
    const int grid = (n_dst + 3) / 4;
    gcmc_gather<<<grid, block, 0, stream>>>(off, src_sorted, node_ids, cj,
                                            weight, ci, out, n_dst);
  }
}